// Round 1
// baseline (50.869 us; speedup 1.0000x reference)
//
#include <hip/hip_runtime.h>

#define CP_NUM 16
#define SEGS   16
#define NAUX   19      // aux control points: aux_first + 17 closed pts + aux_last
#define BLK    256

// One block per batch element. Setup (aux points + centripetal knots) in LDS,
// then 256 threads emit 512 float4 (1024 points x 2 floats) coalesced.
__global__ __launch_bounds__(BLK) void spline_sample_kernel(
    const float* __restrict__ cps, float* __restrict__ out)
{
    __shared__ float s_cp[CP_NUM * 2];
    __shared__ float s_aux[NAUX * 2];
    __shared__ float s_len[NAUX - 1];
    __shared__ float s_t[NAUX];

    const int b = blockIdx.x;
    const int t = threadIdx.x;

    // Stage the 32 floats of control points (8 x float4), coalesced.
    if (t < 8) {
        reinterpret_cast<float4*>(s_cp)[t] =
            reinterpret_cast<const float4*>(cps + (size_t)b * (CP_NUM * 2))[t];
    }
    __syncthreads();

    // Auxiliary control points: aux[0]=aux_first, aux[1..16]=cps[0..15],
    // aux[17]=cps[0] (closure), aux[18]=aux_last.
    if (t < NAUX) {
        const float c0x = s_cp[0],  c0y = s_cp[1];
        const float c1x = s_cp[2],  c1y = s_cp[3];
        const float cLx = s_cp[30], cLy = s_cp[31];   // cps[15]
        const float dx01 = c0x - c1x, dy01 = c0y - c1y;
        const float l01   = sqrtf(dx01 * dx01 + dy01 * dy01 + 1e-7f);
        const float dxl = c0x - cLx, dyl = c0y - cLy; // cc[-1]-cc[-2] = cps0-cps15
        const float llast = sqrtf(dxl * dxl + dyl * dyl + 1e-7f);
        float ax, ay;
        if (t == 0) {
            const float r = l01 / llast;
            ax = c0x - r * dxl;
            ay = c0y - r * dyl;
        } else if (t <= CP_NUM) {          // t in [1,16] -> cps[t-1]
            ax = s_cp[(t - 1) * 2];
            ay = s_cp[(t - 1) * 2 + 1];
        } else if (t == CP_NUM + 1) {      // t == 17 -> cc[16] = cps[0]
            ax = c0x;
            ay = c0y;
        } else {                            // t == 18 -> aux_last
            const float r = llast / l01;
            ax = c0x + r * (c1x - c0x);
            ay = c0y + r * (c1y - c0y);
        }
        s_aux[t * 2]     = ax;
        s_aux[t * 2 + 1] = ay;
    }
    __syncthreads();

    // Centripetal knot increments: (||d||^2)^(1/4) = sqrt(sqrt(sumsq)).
    if (t < NAUX - 1) {
        const float dx = s_aux[(t + 1) * 2]     - s_aux[t * 2];
        const float dy = s_aux[(t + 1) * 2 + 1] - s_aux[t * 2 + 1];
        s_len[t] = sqrtf(sqrtf(dx * dx + dy * dy));
    }
    __syncthreads();

    // Serial 18-element cumsum on thread 0 (trivial vs 8KB of writes/block).
    if (t == 0) {
        float acc = 0.f;
        s_t[0] = 0.f;
        #pragma unroll
        for (int i = 0; i < NAUX - 1; ++i) { acc += s_len[i]; s_t[i + 1] = acc; }
    }
    __syncthreads();

    float* outb = out + (size_t)b * (SEGS * 64 * 2);

    // 512 float4 per batch; 32 float4 per segment (64 pts x 2 floats).
    #pragma unroll
    for (int rep = 0; rep < 2; ++rep) {
        const int f   = t + rep * BLK;     // float4 index 0..511
        const int seg = f >> 5;            // segment 0..15
        const int j0  = (f & 31) * 2;      // even point index within segment

        const float t0 = s_t[seg],     t1 = s_t[seg + 1];
        const float t2 = s_t[seg + 2], t3 = s_t[seg + 3];
        const float p0x = s_aux[seg * 2],     p0y = s_aux[seg * 2 + 1];
        const float p1x = s_aux[seg * 2 + 2], p1y = s_aux[seg * 2 + 3];
        const float p2x = s_aux[seg * 2 + 4], p2y = s_aux[seg * 2 + 5];
        const float p3x = s_aux[seg * 2 + 6], p3y = s_aux[seg * 2 + 7];

        const float r10 = 1.f / (t1 - t0);
        const float r21 = 1.f / (t2 - t1);
        const float r32 = 1.f / (t3 - t2);
        const float r20 = 1.f / (t2 - t0);
        const float r31 = 1.f / (t3 - t1);

        float4 o;
        #pragma unroll
        for (int k = 0; k < 2; ++k) {
            const float u  = (float)(j0 + k) * (1.0f / 63.0f);
            const float tv = t1 + (t2 - t1) * u;

            const float a01 = (t1 - tv) * r10, b01 = (tv - t0) * r10;
            const float a12 = (t2 - tv) * r21, b12 = (tv - t1) * r21;
            const float a23 = (t3 - tv) * r32, b23 = (tv - t2) * r32;

            const float x01x = a01 * p0x + b01 * p1x, x01y = a01 * p0y + b01 * p1y;
            const float x12x = a12 * p1x + b12 * p2x, x12y = a12 * p1y + b12 * p2y;
            const float x23x = a23 * p2x + b23 * p3x, x23y = a23 * p2y + b23 * p3y;

            const float a012 = (t2 - tv) * r20, b012 = (tv - t0) * r20;
            const float a123 = (t3 - tv) * r31, b123 = (tv - t1) * r31;

            const float x012x = a012 * x01x + b012 * x12x;
            const float x012y = a012 * x01y + b012 * x12y;
            const float x123x = a123 * x12x + b123 * x23x;
            const float x123y = a123 * x12y + b123 * x23y;

            const float px = a12 * x012x + b12 * x123x;
            const float py = a12 * x012y + b12 * x123y;
            if (k == 0) { o.x = px; o.y = py; }
            else        { o.z = px; o.w = py; }
        }
        reinterpret_cast<float4*>(outb)[f] = o;
    }
}

extern "C" void kernel_launch(void* const* d_in, const int* in_sizes, int n_in,
                              void* d_out, int out_size, void* d_ws, size_t ws_size,
                              hipStream_t stream) {
    const float* cps = (const float*)d_in[0];
    float* out = (float*)d_out;
    const int B = in_sizes[0] / (CP_NUM * 2);   // 16384
    spline_sample_kernel<<<B, BLK, 0, stream>>>(cps, out);
}

// Round 2
// 27.738 us; speedup vs baseline: 1.8339x; 1.8339x over previous
//
#include <hip/hip_runtime.h>

#define CP_NUM 16
#define SEGS   16
#define WPB    4            // waves (= curves) per block
#define BLK    (WPB * 64)

// One WAVE per curve. Phases are wave-synchronous (no __syncthreads):
//  1. lanes 0..7   stage 32 floats of control points into LDS
//  2. lanes 0..18  compute auxiliary control points aux[19]
//  3. lanes 0..17  centripetal knot increments + 5-step shuffle scan -> t[19]
//  4. lanes 0..15  expand Barry-Goldman to cubic coeffs in s = tv - t1
//  5. all lanes    emit 8 coalesced float4 each via Horner (6 FMA/point)
__global__ __launch_bounds__(BLK) void spline_poly_kernel(
    const float* __restrict__ cps, float* __restrict__ out, int nb)
{
    __shared__ __align__(16) float s_cp [WPB][CP_NUM * 2];
    __shared__ __align__(16) float s_aux[WPB][19 * 2];
    __shared__ __align__(16) float s_t  [WPB][20];
    __shared__ __align__(16) float s_seg[WPB][SEGS][12]; // cx[4] cy[4] dt pad[3]

    const int lane = threadIdx.x & 63;
    const int wv   = threadIdx.x >> 6;
    const int b    = blockIdx.x * WPB + wv;
    if (b >= nb) return;

    // ---- Phase 1: stage control points (8 x float4, coalesced) ----
    if (lane < 8) {
        reinterpret_cast<float4*>(s_cp[wv])[lane] =
            reinterpret_cast<const float4*>(cps + (size_t)b * (CP_NUM * 2))[lane];
    }
    __builtin_amdgcn_wave_barrier();

    // ---- Phase 2: auxiliary points ----
    // aux[0]=aux_first, aux[1..16]=cps[0..15], aux[17]=cps[0], aux[18]=aux_last
    if (lane < 19) {
        const float c0x = s_cp[wv][0],  c0y = s_cp[wv][1];
        const float c1x = s_cp[wv][2],  c1y = s_cp[wv][3];
        const float cLx = s_cp[wv][30], cLy = s_cp[wv][31];
        const float dx01 = c0x - c1x, dy01 = c0y - c1y;
        const float l01   = sqrtf(dx01 * dx01 + dy01 * dy01 + 1e-7f);
        const float dxl = c0x - cLx, dyl = c0y - cLy;     // cc[-1]-cc[-2]
        const float llast = sqrtf(dxl * dxl + dyl * dyl + 1e-7f);
        float ax, ay;
        if (lane == 0) {
            const float r = l01 / llast;
            ax = c0x - r * dxl;  ay = c0y - r * dyl;
        } else if (lane <= CP_NUM) {
            ax = s_cp[wv][(lane - 1) * 2];  ay = s_cp[wv][(lane - 1) * 2 + 1];
        } else if (lane == CP_NUM + 1) {
            ax = c0x;  ay = c0y;
        } else {
            const float r = llast / l01;
            ax = c0x + r * (c1x - c0x);  ay = c0y + r * (c1y - c0y);
        }
        s_aux[wv][lane * 2]     = ax;
        s_aux[wv][lane * 2 + 1] = ay;
    }
    __builtin_amdgcn_wave_barrier();

    // ---- Phase 3: knot increments + wave inclusive scan ----
    float len = 0.f;
    if (lane < 18) {
        const float dx = s_aux[wv][(lane + 1) * 2]     - s_aux[wv][lane * 2];
        const float dy = s_aux[wv][(lane + 1) * 2 + 1] - s_aux[wv][lane * 2 + 1];
        len = sqrtf(sqrtf(dx * dx + dy * dy));   // (||d||^2)^(1/4) = ||d||^0.5
    }
    #pragma unroll
    for (int d = 1; d < 32; d <<= 1) {
        const float n = __shfl_up(len, d);
        if (lane >= d) len += n;
    }
    if (lane == 0) s_t[wv][0] = 0.f;
    if (lane < 18) s_t[wv][lane + 1] = len;
    __builtin_amdgcn_wave_barrier();

    // ---- Phase 4: cubic coefficients per segment (lanes 0..15) ----
    if (lane < SEGS) {
        const float t0 = s_t[wv][lane];
        const float t1 = s_t[wv][lane + 1];
        const float t2 = s_t[wv][lane + 2];
        const float t3 = s_t[wv][lane + 3];
        const float A  = t1 - t0, Bk = t2 - t1, C = t3 - t2;
        const float BC = Bk + C;
        const float r10 = 1.f / A;
        const float r21 = 1.f / Bk;
        const float r32 = 1.f / C;
        const float r20 = 1.f / (A + Bk);
        const float r31 = 1.f / BC;

        float* sp = s_seg[wv][lane];
        #pragma unroll
        for (int d = 0; d < 2; ++d) {   // d=0: x, d=1: y
            const float P0 = s_aux[wv][lane * 2 + d];
            const float P1 = s_aux[wv][lane * 2 + 2 + d];
            const float P2 = s_aux[wv][lane * 2 + 4 + d];
            const float P3 = s_aux[wv][lane * 2 + 6 + d];
            // Linear pyramid legs: value + slope in s
            const float L1c0 = P1,                              L1c1 = (P1 - P0) * r10;
            const float L2c0 = P1,                              L2c1 = (P2 - P1) * r21;
            const float L3c0 = (BC * P2 - Bk * P3) * r32,       L3c1 = (P3 - P2) * r32;
            // Quadratics
            const float Q1c0 = r20 * (Bk * L1c0 + A * L2c0);
            const float Q1c1 = r20 * (Bk * L1c1 - L1c0 + A * L2c1 + L2c0);
            const float Q1c2 = r20 * (L2c1 - L1c1);
            const float Q2c0 = r31 * (BC * L2c0);
            const float Q2c1 = r31 * (BC * L2c1 - L2c0 + L3c0);
            const float Q2c2 = r31 * (L3c1 - L2c1);
            // Cubic: [1,-r21] conv Q1 + [0,r21] conv Q2
            sp[d * 4 + 0] = Q1c0;
            sp[d * 4 + 1] = Q1c1 + r21 * (Q2c0 - Q1c0);
            sp[d * 4 + 2] = Q1c2 + r21 * (Q2c1 - Q1c1);
            sp[d * 4 + 3] = r21 * (Q2c2 - Q1c2);
        }
        sp[8] = Bk;   // t2 - t1: scales u into local parameter s
    }
    __builtin_amdgcn_wave_barrier();

    // ---- Phase 5: emit 1024 points = 512 float4, coalesced ----
    float4* outw = reinterpret_cast<float4*>(out + (size_t)b * (SEGS * 64 * 2));
    #pragma unroll
    for (int i = 0; i < 8; ++i) {
        const int f  = lane + 64 * i;     // float4 index 0..511
        const int sg = f >> 5;            // segment (same for each half-wave)
        const int j  = (f & 31) * 2;      // even point index within segment
        const float* sp = s_seg[wv][sg];
        const float4 cx = *reinterpret_cast<const float4*>(sp);
        const float4 cy = *reinterpret_cast<const float4*>(sp + 4);
        const float dt  = sp[8];
        const float s0 = dt * (float)j       * (1.f / 63.f);
        const float s1 = dt * (float)(j + 1) * (1.f / 63.f);
        float4 o;
        o.x = ((cx.w * s0 + cx.z) * s0 + cx.y) * s0 + cx.x;
        o.y = ((cy.w * s0 + cy.z) * s0 + cy.y) * s0 + cy.x;
        o.z = ((cx.w * s1 + cx.z) * s1 + cx.y) * s1 + cx.x;
        o.w = ((cy.w * s1 + cy.z) * s1 + cy.y) * s1 + cy.x;
        outw[f] = o;
    }
}

extern "C" void kernel_launch(void* const* d_in, const int* in_sizes, int n_in,
                              void* d_out, int out_size, void* d_ws, size_t ws_size,
                              hipStream_t stream) {
    const float* cps = (const float*)d_in[0];
    float* out = (float*)d_out;
    const int B = in_sizes[0] / (CP_NUM * 2);          // 16384
    const int grid = (B + WPB - 1) / WPB;              // 4096
    spline_poly_kernel<<<grid, BLK, 0, stream>>>(cps, out, B);
}